// Round 12
// baseline (218.584 us; speedup 1.0000x reference)
//
#include <hip/hip_runtime.h>
#include <hip/hip_fp16.h>

// ---------------------------------------------------------------------------
// 2-layer GCN on MI355X.
// Structure:
//   build: p1 coarse LDS counting sort -> bscan -> p2 fine CSR (dst-sorted
//          ssrc + row_ptr/deg/dinv). No global float atomics anywhere.
//   layer: h = (X @ W) * dinv[row] via fp16 MFMA (mfma_f32_16x16x32_f16);
//          agg = wave-per-node register accumulate + shfl_xor combine.
// Evidence trail: scattered row-gather runs ~3 TB/s HBM-side; FETCH floor =
//   (#XCDs sharing each slab) x slab bytes. 32B-granule slicing loses to L2
//   request rate (R10); 128B slice = exactly 1 line -> no request inflation.
// R12: h1 split into two 64-col half-slabs [2][N][64] fp16; agg128 slice =
//   blockIdx&1 -> even/odd XCDs -> each half-slab homed on 4 XCDs:
//   FETCH 8x25.6 -> 4x12.8x2 + ssrc x2 ~= 115MB. agg64 row = 1 line already
//   (cannot slice) - unchanged. out1 fp16 (R11).
// ---------------------------------------------------------------------------

typedef _Float16 half8 __attribute__((ext_vector_type(8)));
typedef float f32x4 __attribute__((ext_vector_type(4)));

constexpr int BK_SHIFT = 7;               // 128 nodes per bucket
constexpr int BK_NODES = 1 << BK_SHIFT;
constexpr int NB_MAX   = 1024;
constexpr int SLAB     = 2560;            // mean 2046 + 11 sigma
constexpr int P1_EPT   = 32;
constexpr int P1_EDGES = 256 * P1_EPT;    // 8192

// ---- pass 1: LDS counting sort of 8192 edges into coarse buckets ----
__global__ __launch_bounds__(256) void k_p1(const int* __restrict__ src,
                                            const int* __restrict__ dst, int E,
                                            int NB, int* __restrict__ bfill,
                                            unsigned* __restrict__ slab) {
  __shared__ unsigned stage[P1_EDGES];
  __shared__ unsigned short bidp[P1_EDGES];
  __shared__ int hist[NB_MAX];
  __shared__ int lbase[NB_MAX];
  __shared__ int goff[NB_MAX];
  __shared__ int part[256];

  const int t = threadIdx.x;
  const long base = (long)blockIdx.x * P1_EDGES;
  const int nval = (int)(((long)E - base < (long)P1_EDGES) ? (E - base) : P1_EDGES);

  for (int i = t; i < NB; i += 256) hist[i] = 0;
  __syncthreads();

  int eb[P1_EPT];
  unsigned ev[P1_EPT];
#pragma unroll
  for (int i = 0; i < P1_EPT; ++i) {
    long e = base + t + i * 256;
    int b = -1;
    unsigned v = 0;
    if (e < E) {
      int d = dst[e];
      int s = src[e];
      b = d >> BK_SHIFT;
      v = ((unsigned)(d & (BK_NODES - 1)) << 17) | (unsigned)s;
      atomicAdd(&hist[b], 1);
    }
    eb[i] = b;
    ev[i] = v;
  }
  __syncthreads();

  int lc[4];
  int lsum = 0;
#pragma unroll
  for (int j = 0; j < 4; ++j) {
    int b = t * 4 + j;
    lc[j] = (b < NB) ? hist[b] : 0;
    lsum += lc[j];
  }
  part[t] = lsum;
  __syncthreads();
  for (int o = 1; o < 256; o <<= 1) {
    int a = (t >= o) ? part[t - o] : 0;
    __syncthreads();
    part[t] += a;
    __syncthreads();
  }
  int run = part[t] - lsum;
#pragma unroll
  for (int j = 0; j < 4; ++j) {
    int b = t * 4 + j;
    if (b < NB) lbase[b] = run;
    run += lc[j];
  }
  __syncthreads();

  for (int b = t; b < NB; b += 256) {
    int len = hist[b];
    int g = len ? atomicAdd(&bfill[b], len) : 0;
    goff[b] = b * SLAB + g - lbase[b];
  }
  __syncthreads();

#pragma unroll
  for (int i = 0; i < P1_EPT; ++i) {
    if (eb[i] >= 0) {
      int p = atomicAdd(&lbase[eb[i]], 1);
      stage[p] = ev[i];
      bidp[p] = (unsigned short)eb[i];
    }
  }
  __syncthreads();

  for (int p = t; p < nval; p += 256) {
    int b = bidp[p];
    slab[goff[b] + p] = stage[p];
  }
}

__global__ __launch_bounds__(1024) void k_bscan(const int* __restrict__ bfill, int NB,
                                                int* __restrict__ bbase) {
  __shared__ int sm[1024];
  const int t = threadIdx.x;
  int v = (t < NB) ? bfill[t] : 0;
  sm[t] = v;
  __syncthreads();
  for (int o = 1; o < 1024; o <<= 1) {
    int a = (t >= o) ? sm[t - o] : 0;
    __syncthreads();
    sm[t] += a;
    __syncthreads();
  }
  if (t < NB) bbase[t] = sm[t] - v;
}

// ---- pass 2: per-bucket fine CSR (deg/row_ptr/dinv + dst-sorted ssrc) ----
__global__ __launch_bounds__(256) void k_p2(const unsigned* __restrict__ slab,
                                            const int* __restrict__ bfill,
                                            const int* __restrict__ bbase, int N,
                                            int* __restrict__ deg,
                                            int* __restrict__ row_ptr,
                                            float* __restrict__ dinv,
                                            int* __restrict__ ssrc) {
  __shared__ int hist[BK_NODES];
  __shared__ int lb[BK_NODES];
  const int b = blockIdx.x;
  const int t = threadIdx.x;
  const int len = bfill[b];
  const int gbase = bbase[b];
  const unsigned* seg = slab + (size_t)b * SLAB;

  if (t < BK_NODES) hist[t] = 0;
  __syncthreads();
  for (int i = t; i < len; i += 256) atomicAdd(&hist[seg[i] >> 17], 1);
  __syncthreads();

  if (t < BK_NODES) lb[t] = hist[t];
  __syncthreads();
  for (int o = 1; o < BK_NODES; o <<= 1) {
    int a = 0;
    if (t < BK_NODES && t >= o) a = lb[t - o];
    __syncthreads();
    if (t < BK_NODES) lb[t] += a;
    __syncthreads();
  }

  int n = b * BK_NODES + t;
  if (t < BK_NODES && n < N) {
    int d = hist[t];
    deg[n] = d;
    row_ptr[n] = gbase + lb[t] - d;
    dinv[n] = rsqrtf((float)(d + 1));
  }
  __syncthreads();
  if (t < BK_NODES) lb[t] -= hist[t];
  __syncthreads();

  for (int i = t; i < len; i += 256) {
    unsigned v = seg[i];
    int l = v >> 17;
    int p = atomicAdd(&lb[l], 1);
    ssrc[gbase + p] = (int)(v & 0x1FFFF);
  }
}

// ---- prep: W (fp32, [K][NC]) -> Wt (fp16, [NC][K]) ----
__global__ __launch_bounds__(256) void k_prep(const float* __restrict__ W1,
                                              const float* __restrict__ W2,
                                              __half* __restrict__ Wt1,
                                              __half* __restrict__ Wt2) {
  int i = blockIdx.x * blockDim.x + threadIdx.x;
  if (i < 16384) {
    int k = i >> 7, n = i & 127;
    Wt1[n * 128 + k] = __float2half(W1[i]);
  } else if (i < 24576) {
    int j = i - 16384;
    int k = j >> 6, n = j & 63;
    Wt2[n * 128 + k] = __float2half(W2[j]);
  }
}

// ---- MFMA GEMM: H[row][c] = (sum_k X[row][k]*W[k][c]) * dinv[row], fp16 out.
// IN_HALF: X fp16 [N][128] (layer 2); else fp32 [N][128].
// OUT_SLAB: write [2][N][64] half-slabs (slab = col>>6); else row-major [N][NC].
template <int NC, bool IN_HALF, bool OUT_SLAB>
__global__ __launch_bounds__(256) void k_gemm(const void* __restrict__ Xv,
                                              const __half* __restrict__ Wt,
                                              const float* __restrict__ dinv,
                                              __half* __restrict__ H, int N) {
  constexpr int K = 128;
  constexpr int BM = 64;
  constexpr int LDK = K + 8;
  constexpr int NT = NC / 16;
  __shared__ _Float16 xs[BM * LDK];
  __shared__ _Float16 wl[NC * LDK];

  const int t = threadIdx.x;
  const int r0 = blockIdx.x * BM;

  if (IN_HALF) {
    const __half* X = (const __half*)Xv;
    for (int i = t; i < BM * (K / 8); i += 256) {
      int row = i >> 4, kc = i & 15;
      float4 raw = make_float4(0.f, 0.f, 0.f, 0.f);
      if (r0 + row < N)
        raw = *reinterpret_cast<const float4*>(X + (size_t)(r0 + row) * K + 8 * kc);
      *reinterpret_cast<float4*>(&xs[row * LDK + 8 * kc]) = raw;
    }
  } else {
    const float* X = (const float*)Xv;
    for (int i = t; i < BM * (K / 4); i += 256) {
      int row = i >> 5, kg = i & 31;
      float4 v = make_float4(0.f, 0.f, 0.f, 0.f);
      if (r0 + row < N)
        v = *reinterpret_cast<const float4*>(X + (size_t)(r0 + row) * K + 4 * kg);
      union { _Float16 h[4]; unsigned long long u; } pk;
      pk.h[0] = (_Float16)v.x; pk.h[1] = (_Float16)v.y;
      pk.h[2] = (_Float16)v.z; pk.h[3] = (_Float16)v.w;
      *reinterpret_cast<unsigned long long*>(&xs[row * LDK + 4 * kg]) = pk.u;
    }
  }
  for (int i = t; i < NC * (K / 8); i += 256) {
    int n = i >> 4, kc = i & 15;
    float4 raw = *reinterpret_cast<const float4*>(Wt + (size_t)n * K + 8 * kc);
    *reinterpret_cast<float4*>(&wl[n * LDK + 8 * kc]) = raw;
  }
  __syncthreads();

  const int w = t >> 6;
  const int lane = t & 63;
  const int lm = lane & 15;
  const int lg = lane >> 4;

  half8 a[4];
#pragma unroll
  for (int kt = 0; kt < 4; ++kt)
    a[kt] = *reinterpret_cast<const half8*>(&xs[(w * 16 + lm) * LDK + kt * 32 + lg * 8]);

  f32x4 acc[NT];
#pragma unroll
  for (int nt = 0; nt < NT; ++nt) acc[nt] = (f32x4){0.f, 0.f, 0.f, 0.f};

#pragma unroll
  for (int nt = 0; nt < NT; ++nt) {
#pragma unroll
    for (int kt = 0; kt < 4; ++kt) {
      half8 b = *reinterpret_cast<const half8*>(
          &wl[(nt * 16 + lm) * LDK + kt * 32 + lg * 8]);
      acc[nt] = __builtin_amdgcn_mfma_f32_16x16x32_f16(a[kt], b, acc[nt], 0, 0, 0);
    }
  }

  float dv[4];
#pragma unroll
  for (int r = 0; r < 4; ++r) {
    int row = r0 + w * 16 + lg * 4 + r;
    dv[r] = (row < N) ? dinv[row] : 0.f;
  }
#pragma unroll
  for (int nt = 0; nt < NT; ++nt) {
#pragma unroll
    for (int r = 0; r < 4; ++r) {
      int row = r0 + w * 16 + lg * 4 + r;
      if (row < N) {
        _Float16 val = (_Float16)(acc[nt][r] * dv[r]);
        if (OUT_SLAB) {
          int sl = nt >> 2;
          int cc = (nt & 3) * 16 + lm;
          *(_Float16*)(H + (size_t)sl * N * 64 + (size_t)row * 64 + cc) = val;
        } else {
          *(_Float16*)(H + (size_t)row * NC + nt * 16 + lm) = val;
        }
      }
    }
  }
}

// ---- agg layer1, XCD-paired slices: Hs = [2][N][64] fp16 half-slabs.
// slice = blockIdx&1 -> even/odd XCDs via round-robin dispatch; each 12.8MB
// half-slab homed on 4 XCDs. 8 lanes/edge x 16B (= exactly 1 L2 line),
// 8 edges in flight, shfl_xor combine. out fp16 row-major [N][128] + ReLU.
__global__ __launch_bounds__(256) void k_agg128s(const __half* __restrict__ Hs,
                                                 const int* __restrict__ rp,
                                                 const int* __restrict__ dg,
                                                 const int* __restrict__ ssrc,
                                                 const float* __restrict__ dinv,
                                                 const float* __restrict__ bias,
                                                 __half* __restrict__ out, int N) {
  const int slice = blockIdx.x & 1;
  const int g = blockIdx.x >> 1;
  const int wave = threadIdx.x >> 6;
  const int lane = threadIdx.x & 63;
  const int n = g * 4 + wave;
  if (n >= N) return;

  const int eh = lane >> 3;   // edge slot 0..7
  const int cl = lane & 7;    // 8-col chunk within the 64-col slice
  const __half* __restrict__ sp = Hs + (size_t)slice * N * 64;
  const int e0 = rp[n];
  const int e1 = e0 + dg[n];
  const float dv = dinv[n];

  float acc[8] = {0.f, 0.f, 0.f, 0.f, 0.f, 0.f, 0.f, 0.f};
  auto gat = [&](int s) {
    half8 v = *reinterpret_cast<const half8*>(sp + (size_t)s * 64 + 8 * cl);
#pragma unroll
    for (int j = 0; j < 8; ++j) acc[j] += (float)v[j];
  };
  if (eh == 0) gat(n);  // self loop
  int e = e0;
  for (; e + 16 <= e1; e += 16) {
    int sA = ssrc[e + eh];
    int sB = ssrc[e + 8 + eh];
    gat(sA);
    gat(sB);
  }
  if (e + 8 <= e1) { gat(ssrc[e + eh]); e += 8; }
  if (e + eh < e1) gat(ssrc[e + eh]);

#pragma unroll
  for (int j = 0; j < 8; ++j) {
    acc[j] += __shfl_xor(acc[j], 8);
    acc[j] += __shfl_xor(acc[j], 16);
    acc[j] += __shfl_xor(acc[j], 32);
  }
  if (eh == 0) {
    const float* bp = bias + slice * 64 + 8 * cl;
    float4 b0 = *reinterpret_cast<const float4*>(bp);
    float4 b1 = *reinterpret_cast<const float4*>(bp + 4);
    float o[8];
    o[0] = acc[0] * dv + b0.x; o[1] = acc[1] * dv + b0.y;
    o[2] = acc[2] * dv + b0.z; o[3] = acc[3] * dv + b0.w;
    o[4] = acc[4] * dv + b1.x; o[5] = acc[5] * dv + b1.y;
    o[6] = acc[6] * dv + b1.z; o[7] = acc[7] * dv + b1.w;
    half8 ph;
#pragma unroll
    for (int j = 0; j < 8; ++j) ph[j] = (_Float16)fmaxf(o[j], 0.f);
    *reinterpret_cast<half8*>(out + (size_t)n * 128 + slice * 64 + 8 * cl) = ph;
  }
}

// ---- agg C=64 (unsliced: row = 1 line already): wave per node, 8 lanes/edge ----
__global__ __launch_bounds__(256) void k_agg64(const __half* __restrict__ H,
                                               const int* __restrict__ rp,
                                               const int* __restrict__ dg,
                                               const int* __restrict__ ssrc,
                                               const float* __restrict__ dinv,
                                               const float* __restrict__ bias,
                                               float* __restrict__ out, int N) {
  const int wave = threadIdx.x >> 6;
  const int lane = threadIdx.x & 63;
  const int n = blockIdx.x * 4 + wave;
  if (n >= N) return;

  const int eh = lane >> 3;   // edge slot 0..7
  const int cl = lane & 7;    // 8-col chunk
  const int e0 = rp[n];
  const int e1 = e0 + dg[n];
  const float dv = dinv[n];

  float acc[8] = {0.f, 0.f, 0.f, 0.f, 0.f, 0.f, 0.f, 0.f};
  auto gat = [&](int s) {
    half8 v = *reinterpret_cast<const half8*>(H + (size_t)s * 64 + 8 * cl);
#pragma unroll
    for (int j = 0; j < 8; ++j) acc[j] += (float)v[j];
  };
  if (eh == 0) gat(n);
  int e = e0;
  for (; e + 16 <= e1; e += 16) {
    int sA = ssrc[e + eh];
    int sB = ssrc[e + 8 + eh];
    gat(sA);
    gat(sB);
  }
  if (e + 8 <= e1) { gat(ssrc[e + eh]); e += 8; }
  if (e + eh < e1) gat(ssrc[e + eh]);

#pragma unroll
  for (int j = 0; j < 8; ++j) {
    acc[j] += __shfl_xor(acc[j], 8);
    acc[j] += __shfl_xor(acc[j], 16);
    acc[j] += __shfl_xor(acc[j], 32);
  }
  if (eh == 0) {
    float4 b0 = *reinterpret_cast<const float4*>(bias + 8 * cl);
    float4 b1 = *reinterpret_cast<const float4*>(bias + 8 * cl + 4);
    f32x4 o0, o1;
    o0[0] = acc[0] * dv + b0.x; o0[1] = acc[1] * dv + b0.y;
    o0[2] = acc[2] * dv + b0.z; o0[3] = acc[3] * dv + b0.w;
    o1[0] = acc[4] * dv + b1.x; o1[1] = acc[5] * dv + b1.y;
    o1[2] = acc[6] * dv + b1.z; o1[3] = acc[7] * dv + b1.w;
    float* op = out + (size_t)n * 64 + 8 * cl;
    __builtin_nontemporal_store(o0, reinterpret_cast<f32x4*>(op));
    __builtin_nontemporal_store(o1, reinterpret_cast<f32x4*>(op + 4));
  }
}

extern "C" void kernel_launch(void* const* d_in, const int* in_sizes, int n_in,
                              void* d_out, int out_size, void* d_ws, size_t ws_size,
                              hipStream_t stream) {
  const float* x = (const float*)d_in[0];
  const int* ei = (const int*)d_in[1];
  const float* W1 = (const float*)d_in[2];
  const float* b1 = (const float*)d_in[3];
  const float* W2 = (const float*)d_in[4];
  const float* b2 = (const float*)d_in[5];

  const int K = 128;
  const int N = in_sizes[0] / K;     // 100000
  const int E = in_sizes[1] / 2;     // 1600000
  const int NB = (N + BK_NODES - 1) >> BK_SHIFT;  // 782
  if (NB > NB_MAX) return;

  const int* src = ei;
  const int* dst = ei + E;

  size_t off = 0;
  auto carve = [&](size_t bytes) {
    size_t o = off;
    off += (bytes + 255) & ~(size_t)255;
    return o;
  };
  char* ws = (char*)d_ws;
  int*      deg     = (int*)(ws + carve((size_t)N * 4));
  int*      row_ptr = (int*)(ws + carve((size_t)N * 4));
  float*    dinv    = (float*)(ws + carve((size_t)N * 4));
  int*      bfill   = (int*)(ws + carve((size_t)NB * 4));
  int*      bbase   = (int*)(ws + carve((size_t)NB * 4));
  __half*   wt1     = (__half*)(ws + carve(16384 * 2));
  __half*   wt2     = (__half*)(ws + carve(8192 * 2));
  unsigned* slab    = (unsigned*)(ws + carve((size_t)NB * SLAB * 4));
  int*      ssrc    = (int*)(ws + carve((size_t)E * 4));
  __half*   h1      = (__half*)(ws + carve((size_t)N * K * 2));  // [2][N][64]
  __half*   out1    = (__half*)(ws + carve((size_t)N * K * 2));  // [N][128] fp16
  if (off > ws_size) return;

  __half* h2 = h1;            // h1 dead after agg1; h2 row-major [N][64]
  float* out2 = (float*)d_out;

  (void)hipMemsetAsync(bfill, 0, (size_t)NB * 4, stream);
  k_prep<<<96, 256, 0, stream>>>(W1, W2, wt1, wt2);
  const int nwg1 = (E + P1_EDGES - 1) / P1_EDGES;
  k_p1<<<nwg1, 256, 0, stream>>>(src, dst, E, NB, bfill, slab);
  k_bscan<<<1, 1024, 0, stream>>>(bfill, NB, bbase);
  k_p2<<<NB, 256, 0, stream>>>(slab, bfill, bbase, N, deg, row_ptr, dinv, ssrc);

  k_gemm<128, false, true><<<(N + 63) / 64, 256, 0, stream>>>(x, wt1, dinv, h1, N);
  k_agg128s<<<((N + 3) / 4) * 2, 256, 0, stream>>>(h1, row_ptr, deg, ssrc, dinv,
                                                   b1, out1, N);
  k_gemm<64, true, false><<<(N + 63) / 64, 256, 0, stream>>>(out1, wt2, dinv, h2, N);
  k_agg64<<<(N + 3) / 4, 256, 0, stream>>>(h2, row_ptr, deg, ssrc, dinv, b2,
                                           out2, N);
  (void)n_in; (void)out_size;
}

// Round 13
// 199.349 us; speedup vs baseline: 1.0965x; 1.0965x over previous
//
#include <hip/hip_runtime.h>
#include <hip/hip_fp16.h>

// ---------------------------------------------------------------------------
// 2-layer GCN on MI355X.  (R13 = R11 revert + deeper gather unroll)
// build: p1 coarse LDS counting sort -> bscan -> p2 fine CSR (dst-sorted
//        ssrc + row_ptr/deg/dinv). No global float atomics anywhere.
// layer: h = (X @ W) * dinv[row] via fp16 MFMA; h fp16 row-major;
//        agg = wave-per-node, 16 lanes x 16B/edge (C=128; 8 lanes C=64),
//        4-deep half8 gather unroll, shfl_xor combine. out1 fp16.
// Evidence: column slicing dead at all granules (R7 serial / R10 request-rate
//   / R12 cache-capacity+issue); 8x|h| XCD replication is structural for a
//   random graph; scattered-row gather ceiling ~3.5 TB/s HBM-side
//   (R2/R4/R5/R11 stable). R11 agg128 = 222MB/63.5us = at that ceiling.
// ---------------------------------------------------------------------------

typedef _Float16 half8 __attribute__((ext_vector_type(8)));
typedef float f32x4 __attribute__((ext_vector_type(4)));

constexpr int BK_SHIFT = 7;               // 128 nodes per bucket
constexpr int BK_NODES = 1 << BK_SHIFT;
constexpr int NB_MAX   = 1024;
constexpr int SLAB     = 2560;            // mean 2046 + 11 sigma
constexpr int P1_EPT   = 32;
constexpr int P1_EDGES = 256 * P1_EPT;    // 8192

// ---- pass 1: LDS counting sort of 8192 edges into coarse buckets ----
__global__ __launch_bounds__(256) void k_p1(const int* __restrict__ src,
                                            const int* __restrict__ dst, int E,
                                            int NB, int* __restrict__ bfill,
                                            unsigned* __restrict__ slab) {
  __shared__ unsigned stage[P1_EDGES];
  __shared__ unsigned short bidp[P1_EDGES];
  __shared__ int hist[NB_MAX];
  __shared__ int lbase[NB_MAX];
  __shared__ int goff[NB_MAX];
  __shared__ int part[256];

  const int t = threadIdx.x;
  const long base = (long)blockIdx.x * P1_EDGES;
  const int nval = (int)(((long)E - base < (long)P1_EDGES) ? (E - base) : P1_EDGES);

  for (int i = t; i < NB; i += 256) hist[i] = 0;
  __syncthreads();

  int eb[P1_EPT];
  unsigned ev[P1_EPT];
#pragma unroll
  for (int i = 0; i < P1_EPT; ++i) {
    long e = base + t + i * 256;
    int b = -1;
    unsigned v = 0;
    if (e < E) {
      int d = dst[e];
      int s = src[e];
      b = d >> BK_SHIFT;
      v = ((unsigned)(d & (BK_NODES - 1)) << 17) | (unsigned)s;
      atomicAdd(&hist[b], 1);
    }
    eb[i] = b;
    ev[i] = v;
  }
  __syncthreads();

  int lc[4];
  int lsum = 0;
#pragma unroll
  for (int j = 0; j < 4; ++j) {
    int b = t * 4 + j;
    lc[j] = (b < NB) ? hist[b] : 0;
    lsum += lc[j];
  }
  part[t] = lsum;
  __syncthreads();
  for (int o = 1; o < 256; o <<= 1) {
    int a = (t >= o) ? part[t - o] : 0;
    __syncthreads();
    part[t] += a;
    __syncthreads();
  }
  int run = part[t] - lsum;
#pragma unroll
  for (int j = 0; j < 4; ++j) {
    int b = t * 4 + j;
    if (b < NB) lbase[b] = run;
    run += lc[j];
  }
  __syncthreads();

  for (int b = t; b < NB; b += 256) {
    int len = hist[b];
    int g = len ? atomicAdd(&bfill[b], len) : 0;
    goff[b] = b * SLAB + g - lbase[b];
  }
  __syncthreads();

#pragma unroll
  for (int i = 0; i < P1_EPT; ++i) {
    if (eb[i] >= 0) {
      int p = atomicAdd(&lbase[eb[i]], 1);
      stage[p] = ev[i];
      bidp[p] = (unsigned short)eb[i];
    }
  }
  __syncthreads();

  for (int p = t; p < nval; p += 256) {
    int b = bidp[p];
    slab[goff[b] + p] = stage[p];
  }
}

__global__ __launch_bounds__(1024) void k_bscan(const int* __restrict__ bfill, int NB,
                                                int* __restrict__ bbase) {
  __shared__ int sm[1024];
  const int t = threadIdx.x;
  int v = (t < NB) ? bfill[t] : 0;
  sm[t] = v;
  __syncthreads();
  for (int o = 1; o < 1024; o <<= 1) {
    int a = (t >= o) ? sm[t - o] : 0;
    __syncthreads();
    sm[t] += a;
    __syncthreads();
  }
  if (t < NB) bbase[t] = sm[t] - v;
}

// ---- pass 2: per-bucket fine CSR (deg/row_ptr/dinv + dst-sorted ssrc) ----
__global__ __launch_bounds__(256) void k_p2(const unsigned* __restrict__ slab,
                                            const int* __restrict__ bfill,
                                            const int* __restrict__ bbase, int N,
                                            int* __restrict__ deg,
                                            int* __restrict__ row_ptr,
                                            float* __restrict__ dinv,
                                            int* __restrict__ ssrc) {
  __shared__ int hist[BK_NODES];
  __shared__ int lb[BK_NODES];
  const int b = blockIdx.x;
  const int t = threadIdx.x;
  const int len = bfill[b];
  const int gbase = bbase[b];
  const unsigned* seg = slab + (size_t)b * SLAB;

  if (t < BK_NODES) hist[t] = 0;
  __syncthreads();
  for (int i = t; i < len; i += 256) atomicAdd(&hist[seg[i] >> 17], 1);
  __syncthreads();

  if (t < BK_NODES) lb[t] = hist[t];
  __syncthreads();
  for (int o = 1; o < BK_NODES; o <<= 1) {
    int a = 0;
    if (t < BK_NODES && t >= o) a = lb[t - o];
    __syncthreads();
    if (t < BK_NODES) lb[t] += a;
    __syncthreads();
  }

  int n = b * BK_NODES + t;
  if (t < BK_NODES && n < N) {
    int d = hist[t];
    deg[n] = d;
    row_ptr[n] = gbase + lb[t] - d;
    dinv[n] = rsqrtf((float)(d + 1));
  }
  __syncthreads();
  if (t < BK_NODES) lb[t] -= hist[t];
  __syncthreads();

  for (int i = t; i < len; i += 256) {
    unsigned v = seg[i];
    int l = v >> 17;
    int p = atomicAdd(&lb[l], 1);
    ssrc[gbase + p] = (int)(v & 0x1FFFF);
  }
}

// ---- prep: W (fp32, [K][NC]) -> Wt (fp16, [NC][K]) ----
__global__ __launch_bounds__(256) void k_prep(const float* __restrict__ W1,
                                              const float* __restrict__ W2,
                                              __half* __restrict__ Wt1,
                                              __half* __restrict__ Wt2) {
  int i = blockIdx.x * blockDim.x + threadIdx.x;
  if (i < 16384) {
    int k = i >> 7, n = i & 127;
    Wt1[n * 128 + k] = __float2half(W1[i]);
  } else if (i < 24576) {
    int j = i - 16384;
    int k = j >> 6, n = j & 63;
    Wt2[n * 128 + k] = __float2half(W2[j]);
  }
}

// ---- MFMA GEMM: H[row][c] = (sum_k X[row][k]*W[k][c]) * dinv[row], fp16 out.
// IN_HALF: X is fp16 [N][128] (layer 2, = out1); else fp32 [N][128].
template <int NC, bool IN_HALF>
__global__ __launch_bounds__(256) void k_gemm(const void* __restrict__ Xv,
                                              const __half* __restrict__ Wt,
                                              const float* __restrict__ dinv,
                                              __half* __restrict__ H, int N) {
  constexpr int K = 128;
  constexpr int BM = 64;
  constexpr int LDK = K + 8;
  constexpr int NT = NC / 16;
  __shared__ _Float16 xs[BM * LDK];
  __shared__ _Float16 wl[NC * LDK];

  const int t = threadIdx.x;
  const int r0 = blockIdx.x * BM;

  if (IN_HALF) {
    const __half* X = (const __half*)Xv;
    for (int i = t; i < BM * (K / 8); i += 256) {
      int row = i >> 4, kc = i & 15;
      float4 raw = make_float4(0.f, 0.f, 0.f, 0.f);
      if (r0 + row < N)
        raw = *reinterpret_cast<const float4*>(X + (size_t)(r0 + row) * K + 8 * kc);
      *reinterpret_cast<float4*>(&xs[row * LDK + 8 * kc]) = raw;
    }
  } else {
    const float* X = (const float*)Xv;
    for (int i = t; i < BM * (K / 4); i += 256) {
      int row = i >> 5, kg = i & 31;
      float4 v = make_float4(0.f, 0.f, 0.f, 0.f);
      if (r0 + row < N)
        v = *reinterpret_cast<const float4*>(X + (size_t)(r0 + row) * K + 4 * kg);
      union { _Float16 h[4]; unsigned long long u; } pk;
      pk.h[0] = (_Float16)v.x; pk.h[1] = (_Float16)v.y;
      pk.h[2] = (_Float16)v.z; pk.h[3] = (_Float16)v.w;
      *reinterpret_cast<unsigned long long*>(&xs[row * LDK + 4 * kg]) = pk.u;
    }
  }
  for (int i = t; i < NC * (K / 8); i += 256) {
    int n = i >> 4, kc = i & 15;
    float4 raw = *reinterpret_cast<const float4*>(Wt + (size_t)n * K + 8 * kc);
    *reinterpret_cast<float4*>(&wl[n * LDK + 8 * kc]) = raw;
  }
  __syncthreads();

  const int w = t >> 6;
  const int lane = t & 63;
  const int lm = lane & 15;
  const int lg = lane >> 4;

  half8 a[4];
#pragma unroll
  for (int kt = 0; kt < 4; ++kt)
    a[kt] = *reinterpret_cast<const half8*>(&xs[(w * 16 + lm) * LDK + kt * 32 + lg * 8]);

  f32x4 acc[NT];
#pragma unroll
  for (int nt = 0; nt < NT; ++nt) acc[nt] = (f32x4){0.f, 0.f, 0.f, 0.f};

#pragma unroll
  for (int nt = 0; nt < NT; ++nt) {
#pragma unroll
    for (int kt = 0; kt < 4; ++kt) {
      half8 b = *reinterpret_cast<const half8*>(
          &wl[(nt * 16 + lm) * LDK + kt * 32 + lg * 8]);
      acc[nt] = __builtin_amdgcn_mfma_f32_16x16x32_f16(a[kt], b, acc[nt], 0, 0, 0);
    }
  }

  float dv[4];
#pragma unroll
  for (int r = 0; r < 4; ++r) {
    int row = r0 + w * 16 + lg * 4 + r;
    dv[r] = (row < N) ? dinv[row] : 0.f;
  }
#pragma unroll
  for (int nt = 0; nt < NT; ++nt) {
#pragma unroll
    for (int r = 0; r < 4; ++r) {
      int row = r0 + w * 16 + lg * 4 + r;
      if (row < N)
        H[(size_t)row * NC + nt * 16 + lm] = __float2half(acc[nt][r] * dv[r]);
    }
  }
}

// ---- agg C=128: wave per node, 16 lanes/edge (16B), 4-deep gather unroll ----
// out fp16 row-major (feeds gemm2 directly). RELU applied.
__global__ __launch_bounds__(256) void k_agg128(const __half* __restrict__ H,
                                                const int* __restrict__ rp,
                                                const int* __restrict__ dg,
                                                const int* __restrict__ ssrc,
                                                const float* __restrict__ dinv,
                                                const float* __restrict__ bias,
                                                __half* __restrict__ out, int N) {
  const int wave = threadIdx.x >> 6;
  const int lane = threadIdx.x & 63;
  const int n = blockIdx.x * 4 + wave;
  if (n >= N) return;

  const int eh = lane >> 4;   // edge slot 0..3
  const int cl = lane & 15;   // 8-col chunk
  const int e0 = rp[n];
  const int e1 = e0 + dg[n];
  const float dv = dinv[n];

  float acc[8] = {0.f, 0.f, 0.f, 0.f, 0.f, 0.f, 0.f, 0.f};
  auto gat = [&](int s) {
    half8 v = *reinterpret_cast<const half8*>(H + (size_t)s * 128 + 8 * cl);
#pragma unroll
    for (int j = 0; j < 8; ++j) acc[j] += (float)v[j];
  };
  if (eh == 0) gat(n);  // self loop
  int e = e0;
  for (; e + 16 <= e1; e += 16) {   // 16 edges per iteration, 4 loads in flight
    int s0 = ssrc[e + eh];
    int s1 = ssrc[e + 4 + eh];
    int s2 = ssrc[e + 8 + eh];
    int s3 = ssrc[e + 12 + eh];
    gat(s0); gat(s1); gat(s2); gat(s3);
  }
  if (e + 8 <= e1) {
    int s0 = ssrc[e + eh];
    int s1 = ssrc[e + 4 + eh];
    gat(s0); gat(s1);
    e += 8;
  }
  if (e + 4 <= e1) { gat(ssrc[e + eh]); e += 4; }
  if (e + eh < e1) gat(ssrc[e + eh]);

#pragma unroll
  for (int j = 0; j < 8; ++j) {
    acc[j] += __shfl_xor(acc[j], 16);
    acc[j] += __shfl_xor(acc[j], 32);
  }
  if (eh == 0) {
    float4 b0 = *reinterpret_cast<const float4*>(bias + 8 * cl);
    float4 b1 = *reinterpret_cast<const float4*>(bias + 8 * cl + 4);
    float o[8];
    o[0] = acc[0] * dv + b0.x; o[1] = acc[1] * dv + b0.y;
    o[2] = acc[2] * dv + b0.z; o[3] = acc[3] * dv + b0.w;
    o[4] = acc[4] * dv + b1.x; o[5] = acc[5] * dv + b1.y;
    o[6] = acc[6] * dv + b1.z; o[7] = acc[7] * dv + b1.w;
    half8 ph;
#pragma unroll
    for (int j = 0; j < 8; ++j) ph[j] = (_Float16)fmaxf(o[j], 0.f);
    *reinterpret_cast<half8*>(out + (size_t)n * 128 + 8 * cl) = ph;
  }
}

// ---- agg C=64: wave per node, 8 lanes/edge (16B), 4-deep gather unroll ----
// out fp32 row-major (= d_out). No relu.
__global__ __launch_bounds__(256) void k_agg64(const __half* __restrict__ H,
                                               const int* __restrict__ rp,
                                               const int* __restrict__ dg,
                                               const int* __restrict__ ssrc,
                                               const float* __restrict__ dinv,
                                               const float* __restrict__ bias,
                                               float* __restrict__ out, int N) {
  const int wave = threadIdx.x >> 6;
  const int lane = threadIdx.x & 63;
  const int n = blockIdx.x * 4 + wave;
  if (n >= N) return;

  const int eh = lane >> 3;   // edge slot 0..7
  const int cl = lane & 7;    // 8-col chunk
  const int e0 = rp[n];
  const int e1 = e0 + dg[n];
  const float dv = dinv[n];

  float acc[8] = {0.f, 0.f, 0.f, 0.f, 0.f, 0.f, 0.f, 0.f};
  auto gat = [&](int s) {
    half8 v = *reinterpret_cast<const half8*>(H + (size_t)s * 64 + 8 * cl);
#pragma unroll
    for (int j = 0; j < 8; ++j) acc[j] += (float)v[j];
  };
  if (eh == 0) gat(n);
  int e = e0;
  for (; e + 32 <= e1; e += 32) {   // 32 edges per iteration, 4 loads in flight
    int s0 = ssrc[e + eh];
    int s1 = ssrc[e + 8 + eh];
    int s2 = ssrc[e + 16 + eh];
    int s3 = ssrc[e + 24 + eh];
    gat(s0); gat(s1); gat(s2); gat(s3);
  }
  if (e + 16 <= e1) {
    int s0 = ssrc[e + eh];
    int s1 = ssrc[e + 8 + eh];
    gat(s0); gat(s1);
    e += 16;
  }
  if (e + 8 <= e1) { gat(ssrc[e + eh]); e += 8; }
  if (e + eh < e1) gat(ssrc[e + eh]);

#pragma unroll
  for (int j = 0; j < 8; ++j) {
    acc[j] += __shfl_xor(acc[j], 8);
    acc[j] += __shfl_xor(acc[j], 16);
    acc[j] += __shfl_xor(acc[j], 32);
  }
  if (eh == 0) {
    float4 b0 = *reinterpret_cast<const float4*>(bias + 8 * cl);
    float4 b1 = *reinterpret_cast<const float4*>(bias + 8 * cl + 4);
    f32x4 o0, o1;
    o0[0] = acc[0] * dv + b0.x; o0[1] = acc[1] * dv + b0.y;
    o0[2] = acc[2] * dv + b0.z; o0[3] = acc[3] * dv + b0.w;
    o1[0] = acc[4] * dv + b1.x; o1[1] = acc[5] * dv + b1.y;
    o1[2] = acc[6] * dv + b1.z; o1[3] = acc[7] * dv + b1.w;
    float* op = out + (size_t)n * 64 + 8 * cl;
    __builtin_nontemporal_store(o0, reinterpret_cast<f32x4*>(op));
    __builtin_nontemporal_store(o1, reinterpret_cast<f32x4*>(op + 4));
  }
}

extern "C" void kernel_launch(void* const* d_in, const int* in_sizes, int n_in,
                              void* d_out, int out_size, void* d_ws, size_t ws_size,
                              hipStream_t stream) {
  const float* x = (const float*)d_in[0];
  const int* ei = (const int*)d_in[1];
  const float* W1 = (const float*)d_in[2];
  const float* b1 = (const float*)d_in[3];
  const float* W2 = (const float*)d_in[4];
  const float* b2 = (const float*)d_in[5];

  const int K = 128;
  const int N = in_sizes[0] / K;     // 100000
  const int E = in_sizes[1] / 2;     // 1600000
  const int NB = (N + BK_NODES - 1) >> BK_SHIFT;  // 782
  if (NB > NB_MAX) return;

  const int* src = ei;
  const int* dst = ei + E;

  size_t off = 0;
  auto carve = [&](size_t bytes) {
    size_t o = off;
    off += (bytes + 255) & ~(size_t)255;
    return o;
  };
  char* ws = (char*)d_ws;
  int*      deg     = (int*)(ws + carve((size_t)N * 4));
  int*      row_ptr = (int*)(ws + carve((size_t)N * 4));
  float*    dinv    = (float*)(ws + carve((size_t)N * 4));
  int*      bfill   = (int*)(ws + carve((size_t)NB * 4));
  int*      bbase   = (int*)(ws + carve((size_t)NB * 4));
  __half*   wt1     = (__half*)(ws + carve(16384 * 2));
  __half*   wt2     = (__half*)(ws + carve(8192 * 2));
  unsigned* slab    = (unsigned*)(ws + carve((size_t)NB * SLAB * 4));
  int*      ssrc    = (int*)(ws + carve((size_t)E * 4));
  __half*   h1      = (__half*)(ws + carve((size_t)N * K * 2));  // row-major
  __half*   out1    = (__half*)(ws + carve((size_t)N * K * 2));  // fp16
  if (off > ws_size) return;

  __half* h2 = h1;            // h1 dead after agg1; h2 row-major [N][64]
  float* out2 = (float*)d_out;

  (void)hipMemsetAsync(bfill, 0, (size_t)NB * 4, stream);
  k_prep<<<96, 256, 0, stream>>>(W1, W2, wt1, wt2);
  const int nwg1 = (E + P1_EDGES - 1) / P1_EDGES;
  k_p1<<<nwg1, 256, 0, stream>>>(src, dst, E, NB, bfill, slab);
  k_bscan<<<1, 1024, 0, stream>>>(bfill, NB, bbase);
  k_p2<<<NB, 256, 0, stream>>>(slab, bfill, bbase, N, deg, row_ptr, dinv, ssrc);

  k_gemm<128, false><<<(N + 63) / 64, 256, 0, stream>>>(x, wt1, dinv, h1, N);
  k_agg128<<<(N + 3) / 4, 256, 0, stream>>>(h1, row_ptr, deg, ssrc, dinv, b1,
                                            out1, N);
  k_gemm<64, true><<<(N + 63) / 64, 256, 0, stream>>>(out1, wt2, dinv, h2, N);
  k_agg64<<<(N + 3) / 4, 256, 0, stream>>>(h2, row_ptr, deg, ssrc, dinv, b2,
                                           out2, N);
  (void)n_in; (void)out_size;
}

// Round 14
// 191.899 us; speedup vs baseline: 1.1391x; 1.0388x over previous
//
#include <hip/hip_runtime.h>
#include <hip/hip_fp16.h>

// ---------------------------------------------------------------------------
// 2-layer GCN on MI355X.  (R14 = R13 + build-chain trim: bscan deleted via
// fixed per-bucket ssrc slabs; bfill zeroing folded into k_prep.)
// build: p1 coarse LDS counting sort -> p2 fine CSR (dst-sorted ssrc at
//        b*SLAB fixed offsets + row_ptr/deg/dinv). No global float atomics.
// layer: h = (X @ W) * dinv[row] via fp16 MFMA; h fp16 row-major;
//        agg = wave-per-node, 16 lanes x 16B/edge (C=128; 8 lanes C=64),
//        4-deep half8 gather unroll, shfl_xor combine. out1 fp16.
// Ceiling evidence: agg128 FETCH=192MB=8x|h1| (structural XCD replication,
//   random graph) at ~3.5 TB/s scattered-128B-line rate; unroll-depth
//   neutral (R13) => request/byte-bound, not latency. Slicing dead at all
//   granules (R7 serial / R10 request-rate / R12 capacity+issue).
// ---------------------------------------------------------------------------

typedef _Float16 half8 __attribute__((ext_vector_type(8)));
typedef float f32x4 __attribute__((ext_vector_type(4)));

constexpr int BK_SHIFT = 7;               // 128 nodes per bucket
constexpr int BK_NODES = 1 << BK_SHIFT;
constexpr int NB_MAX   = 1024;
constexpr int SLAB     = 2560;            // mean 2046 + 11 sigma
constexpr int P1_EPT   = 32;
constexpr int P1_EDGES = 256 * P1_EPT;    // 8192

// ---- prep: W -> Wt fp16 transposed; also zero bfill (replaces memset) ----
__global__ __launch_bounds__(256) void k_prep(const float* __restrict__ W1,
                                              const float* __restrict__ W2,
                                              __half* __restrict__ Wt1,
                                              __half* __restrict__ Wt2,
                                              int* __restrict__ bfill, int NB) {
  int i = blockIdx.x * blockDim.x + threadIdx.x;
  if (i < NB) bfill[i] = 0;
  if (i < 16384) {
    int k = i >> 7, n = i & 127;
    Wt1[n * 128 + k] = __float2half(W1[i]);
  } else if (i < 24576) {
    int j = i - 16384;
    int k = j >> 6, n = j & 63;
    Wt2[n * 128 + k] = __float2half(W2[j]);
  }
}

// ---- pass 1: LDS counting sort of 8192 edges into coarse buckets ----
__global__ __launch_bounds__(256) void k_p1(const int* __restrict__ src,
                                            const int* __restrict__ dst, int E,
                                            int NB, int* __restrict__ bfill,
                                            unsigned* __restrict__ slab) {
  __shared__ unsigned stage[P1_EDGES];
  __shared__ unsigned short bidp[P1_EDGES];
  __shared__ int hist[NB_MAX];
  __shared__ int lbase[NB_MAX];
  __shared__ int goff[NB_MAX];
  __shared__ int part[256];

  const int t = threadIdx.x;
  const long base = (long)blockIdx.x * P1_EDGES;
  const int nval = (int)(((long)E - base < (long)P1_EDGES) ? (E - base) : P1_EDGES);

  for (int i = t; i < NB; i += 256) hist[i] = 0;
  __syncthreads();

  int eb[P1_EPT];
  unsigned ev[P1_EPT];
#pragma unroll
  for (int i = 0; i < P1_EPT; ++i) {
    long e = base + t + i * 256;
    int b = -1;
    unsigned v = 0;
    if (e < E) {
      int d = dst[e];
      int s = src[e];
      b = d >> BK_SHIFT;
      v = ((unsigned)(d & (BK_NODES - 1)) << 17) | (unsigned)s;
      atomicAdd(&hist[b], 1);
    }
    eb[i] = b;
    ev[i] = v;
  }
  __syncthreads();

  int lc[4];
  int lsum = 0;
#pragma unroll
  for (int j = 0; j < 4; ++j) {
    int b = t * 4 + j;
    lc[j] = (b < NB) ? hist[b] : 0;
    lsum += lc[j];
  }
  part[t] = lsum;
  __syncthreads();
  for (int o = 1; o < 256; o <<= 1) {
    int a = (t >= o) ? part[t - o] : 0;
    __syncthreads();
    part[t] += a;
    __syncthreads();
  }
  int run = part[t] - lsum;
#pragma unroll
  for (int j = 0; j < 4; ++j) {
    int b = t * 4 + j;
    if (b < NB) lbase[b] = run;
    run += lc[j];
  }
  __syncthreads();

  for (int b = t; b < NB; b += 256) {
    int len = hist[b];
    int g = len ? atomicAdd(&bfill[b], len) : 0;
    goff[b] = b * SLAB + g - lbase[b];
  }
  __syncthreads();

#pragma unroll
  for (int i = 0; i < P1_EPT; ++i) {
    if (eb[i] >= 0) {
      int p = atomicAdd(&lbase[eb[i]], 1);
      stage[p] = ev[i];
      bidp[p] = (unsigned short)eb[i];
    }
  }
  __syncthreads();

  for (int p = t; p < nval; p += 256) {
    int b = bidp[p];
    slab[goff[b] + p] = stage[p];
  }
}

// ---- pass 2: per-bucket fine CSR; ssrc at fixed base b*SLAB (no bscan) ----
__global__ __launch_bounds__(256) void k_p2(const unsigned* __restrict__ slab,
                                            const int* __restrict__ bfill, int N,
                                            int* __restrict__ deg,
                                            int* __restrict__ row_ptr,
                                            float* __restrict__ dinv,
                                            int* __restrict__ ssrc) {
  __shared__ int hist[BK_NODES];
  __shared__ int lb[BK_NODES];
  const int b = blockIdx.x;
  const int t = threadIdx.x;
  int len = bfill[b];
  if (len > SLAB) len = SLAB;
  const int gbase = b * SLAB;
  const unsigned* seg = slab + (size_t)b * SLAB;

  if (t < BK_NODES) hist[t] = 0;
  __syncthreads();
  for (int i = t; i < len; i += 256) atomicAdd(&hist[seg[i] >> 17], 1);
  __syncthreads();

  if (t < BK_NODES) lb[t] = hist[t];
  __syncthreads();
  for (int o = 1; o < BK_NODES; o <<= 1) {
    int a = 0;
    if (t < BK_NODES && t >= o) a = lb[t - o];
    __syncthreads();
    if (t < BK_NODES) lb[t] += a;
    __syncthreads();
  }

  int n = b * BK_NODES + t;
  if (t < BK_NODES && n < N) {
    int d = hist[t];
    deg[n] = d;
    row_ptr[n] = gbase + lb[t] - d;
    dinv[n] = rsqrtf((float)(d + 1));
  }
  __syncthreads();
  if (t < BK_NODES) lb[t] -= hist[t];
  __syncthreads();

  for (int i = t; i < len; i += 256) {
    unsigned v = seg[i];
    int l = v >> 17;
    int p = atomicAdd(&lb[l], 1);
    ssrc[gbase + p] = (int)(v & 0x1FFFF);
  }
}

// ---- MFMA GEMM: H[row][c] = (sum_k X[row][k]*W[k][c]) * dinv[row], fp16 out.
// IN_HALF: X is fp16 [N][128] (layer 2, = out1); else fp32 [N][128].
template <int NC, bool IN_HALF>
__global__ __launch_bounds__(256) void k_gemm(const void* __restrict__ Xv,
                                              const __half* __restrict__ Wt,
                                              const float* __restrict__ dinv,
                                              __half* __restrict__ H, int N) {
  constexpr int K = 128;
  constexpr int BM = 64;
  constexpr int LDK = K + 8;
  constexpr int NT = NC / 16;
  __shared__ _Float16 xs[BM * LDK];
  __shared__ _Float16 wl[NC * LDK];

  const int t = threadIdx.x;
  const int r0 = blockIdx.x * BM;

  if (IN_HALF) {
    const __half* X = (const __half*)Xv;
    for (int i = t; i < BM * (K / 8); i += 256) {
      int row = i >> 4, kc = i & 15;
      float4 raw = make_float4(0.f, 0.f, 0.f, 0.f);
      if (r0 + row < N)
        raw = *reinterpret_cast<const float4*>(X + (size_t)(r0 + row) * K + 8 * kc);
      *reinterpret_cast<float4*>(&xs[row * LDK + 8 * kc]) = raw;
    }
  } else {
    const float* X = (const float*)Xv;
    for (int i = t; i < BM * (K / 4); i += 256) {
      int row = i >> 5, kg = i & 31;
      float4 v = make_float4(0.f, 0.f, 0.f, 0.f);
      if (r0 + row < N)
        v = *reinterpret_cast<const float4*>(X + (size_t)(r0 + row) * K + 4 * kg);
      union { _Float16 h[4]; unsigned long long u; } pk;
      pk.h[0] = (_Float16)v.x; pk.h[1] = (_Float16)v.y;
      pk.h[2] = (_Float16)v.z; pk.h[3] = (_Float16)v.w;
      *reinterpret_cast<unsigned long long*>(&xs[row * LDK + 4 * kg]) = pk.u;
    }
  }
  for (int i = t; i < NC * (K / 8); i += 256) {
    int n = i >> 4, kc = i & 15;
    float4 raw = *reinterpret_cast<const float4*>(Wt + (size_t)n * K + 8 * kc);
    *reinterpret_cast<float4*>(&wl[n * LDK + 8 * kc]) = raw;
  }
  __syncthreads();

  const int w = t >> 6;
  const int lane = t & 63;
  const int lm = lane & 15;
  const int lg = lane >> 4;

  half8 a[4];
#pragma unroll
  for (int kt = 0; kt < 4; ++kt)
    a[kt] = *reinterpret_cast<const half8*>(&xs[(w * 16 + lm) * LDK + kt * 32 + lg * 8]);

  f32x4 acc[NT];
#pragma unroll
  for (int nt = 0; nt < NT; ++nt) acc[nt] = (f32x4){0.f, 0.f, 0.f, 0.f};

#pragma unroll
  for (int nt = 0; nt < NT; ++nt) {
#pragma unroll
    for (int kt = 0; kt < 4; ++kt) {
      half8 b = *reinterpret_cast<const half8*>(
          &wl[(nt * 16 + lm) * LDK + kt * 32 + lg * 8]);
      acc[nt] = __builtin_amdgcn_mfma_f32_16x16x32_f16(a[kt], b, acc[nt], 0, 0, 0);
    }
  }

  float dv[4];
#pragma unroll
  for (int r = 0; r < 4; ++r) {
    int row = r0 + w * 16 + lg * 4 + r;
    dv[r] = (row < N) ? dinv[row] : 0.f;
  }
#pragma unroll
  for (int nt = 0; nt < NT; ++nt) {
#pragma unroll
    for (int r = 0; r < 4; ++r) {
      int row = r0 + w * 16 + lg * 4 + r;
      if (row < N)
        H[(size_t)row * NC + nt * 16 + lm] = __float2half(acc[nt][r] * dv[r]);
    }
  }
}

// ---- agg C=128: wave per node, 16 lanes/edge (16B), 4-deep gather unroll ----
__global__ __launch_bounds__(256) void k_agg128(const __half* __restrict__ H,
                                                const int* __restrict__ rp,
                                                const int* __restrict__ dg,
                                                const int* __restrict__ ssrc,
                                                const float* __restrict__ dinv,
                                                const float* __restrict__ bias,
                                                __half* __restrict__ out, int N) {
  const int wave = threadIdx.x >> 6;
  const int lane = threadIdx.x & 63;
  const int n = blockIdx.x * 4 + wave;
  if (n >= N) return;

  const int eh = lane >> 4;   // edge slot 0..3
  const int cl = lane & 15;   // 8-col chunk
  const int e0 = rp[n];
  const int e1 = e0 + dg[n];
  const float dv = dinv[n];

  float acc[8] = {0.f, 0.f, 0.f, 0.f, 0.f, 0.f, 0.f, 0.f};
  auto gat = [&](int s) {
    half8 v = *reinterpret_cast<const half8*>(H + (size_t)s * 128 + 8 * cl);
#pragma unroll
    for (int j = 0; j < 8; ++j) acc[j] += (float)v[j];
  };
  if (eh == 0) gat(n);  // self loop
  int e = e0;
  for (; e + 16 <= e1; e += 16) {
    int s0 = ssrc[e + eh];
    int s1 = ssrc[e + 4 + eh];
    int s2 = ssrc[e + 8 + eh];
    int s3 = ssrc[e + 12 + eh];
    gat(s0); gat(s1); gat(s2); gat(s3);
  }
  if (e + 8 <= e1) {
    int s0 = ssrc[e + eh];
    int s1 = ssrc[e + 4 + eh];
    gat(s0); gat(s1);
    e += 8;
  }
  if (e + 4 <= e1) { gat(ssrc[e + eh]); e += 4; }
  if (e + eh < e1) gat(ssrc[e + eh]);

#pragma unroll
  for (int j = 0; j < 8; ++j) {
    acc[j] += __shfl_xor(acc[j], 16);
    acc[j] += __shfl_xor(acc[j], 32);
  }
  if (eh == 0) {
    float4 b0 = *reinterpret_cast<const float4*>(bias + 8 * cl);
    float4 b1 = *reinterpret_cast<const float4*>(bias + 8 * cl + 4);
    float o[8];
    o[0] = acc[0] * dv + b0.x; o[1] = acc[1] * dv + b0.y;
    o[2] = acc[2] * dv + b0.z; o[3] = acc[3] * dv + b0.w;
    o[4] = acc[4] * dv + b1.x; o[5] = acc[5] * dv + b1.y;
    o[6] = acc[6] * dv + b1.z; o[7] = acc[7] * dv + b1.w;
    half8 ph;
#pragma unroll
    for (int j = 0; j < 8; ++j) ph[j] = (_Float16)fmaxf(o[j], 0.f);
    *reinterpret_cast<half8*>(out + (size_t)n * 128 + 8 * cl) = ph;
  }
}

// ---- agg C=64: wave per node, 8 lanes/edge (16B), 4-deep gather unroll ----
__global__ __launch_bounds__(256) void k_agg64(const __half* __restrict__ H,
                                               const int* __restrict__ rp,
                                               const int* __restrict__ dg,
                                               const int* __restrict__ ssrc,
                                               const float* __restrict__ dinv,
                                               const float* __restrict__ bias,
                                               float* __restrict__ out, int N) {
  const int wave = threadIdx.x >> 6;
  const int lane = threadIdx.x & 63;
  const int n = blockIdx.x * 4 + wave;
  if (n >= N) return;

  const int eh = lane >> 3;   // edge slot 0..7
  const int cl = lane & 7;    // 8-col chunk
  const int e0 = rp[n];
  const int e1 = e0 + dg[n];
  const float dv = dinv[n];

  float acc[8] = {0.f, 0.f, 0.f, 0.f, 0.f, 0.f, 0.f, 0.f};
  auto gat = [&](int s) {
    half8 v = *reinterpret_cast<const half8*>(H + (size_t)s * 64 + 8 * cl);
#pragma unroll
    for (int j = 0; j < 8; ++j) acc[j] += (float)v[j];
  };
  if (eh == 0) gat(n);
  int e = e0;
  for (; e + 32 <= e1; e += 32) {
    int s0 = ssrc[e + eh];
    int s1 = ssrc[e + 8 + eh];
    int s2 = ssrc[e + 16 + eh];
    int s3 = ssrc[e + 24 + eh];
    gat(s0); gat(s1); gat(s2); gat(s3);
  }
  if (e + 16 <= e1) {
    int s0 = ssrc[e + eh];
    int s1 = ssrc[e + 8 + eh];
    gat(s0); gat(s1);
    e += 16;
  }
  if (e + 8 <= e1) { gat(ssrc[e + eh]); e += 8; }
  if (e + eh < e1) gat(ssrc[e + eh]);

#pragma unroll
  for (int j = 0; j < 8; ++j) {
    acc[j] += __shfl_xor(acc[j], 8);
    acc[j] += __shfl_xor(acc[j], 16);
    acc[j] += __shfl_xor(acc[j], 32);
  }
  if (eh == 0) {
    float4 b0 = *reinterpret_cast<const float4*>(bias + 8 * cl);
    float4 b1 = *reinterpret_cast<const float4*>(bias + 8 * cl + 4);
    f32x4 o0, o1;
    o0[0] = acc[0] * dv + b0.x; o0[1] = acc[1] * dv + b0.y;
    o0[2] = acc[2] * dv + b0.z; o0[3] = acc[3] * dv + b0.w;
    o1[0] = acc[4] * dv + b1.x; o1[1] = acc[5] * dv + b1.y;
    o1[2] = acc[6] * dv + b1.z; o1[3] = acc[7] * dv + b1.w;
    float* op = out + (size_t)n * 64 + 8 * cl;
    __builtin_nontemporal_store(o0, reinterpret_cast<f32x4*>(op));
    __builtin_nontemporal_store(o1, reinterpret_cast<f32x4*>(op + 4));
  }
}

extern "C" void kernel_launch(void* const* d_in, const int* in_sizes, int n_in,
                              void* d_out, int out_size, void* d_ws, size_t ws_size,
                              hipStream_t stream) {
  const float* x = (const float*)d_in[0];
  const int* ei = (const int*)d_in[1];
  const float* W1 = (const float*)d_in[2];
  const float* b1 = (const float*)d_in[3];
  const float* W2 = (const float*)d_in[4];
  const float* b2 = (const float*)d_in[5];

  const int K = 128;
  const int N = in_sizes[0] / K;     // 100000
  const int E = in_sizes[1] / 2;     // 1600000
  const int NB = (N + BK_NODES - 1) >> BK_SHIFT;  // 782
  if (NB > NB_MAX) return;

  const int* src = ei;
  const int* dst = ei + E;

  size_t off = 0;
  auto carve = [&](size_t bytes) {
    size_t o = off;
    off += (bytes + 255) & ~(size_t)255;
    return o;
  };
  char* ws = (char*)d_ws;
  int*      deg     = (int*)(ws + carve((size_t)N * 4));
  int*      row_ptr = (int*)(ws + carve((size_t)N * 4));
  float*    dinv    = (float*)(ws + carve((size_t)N * 4));
  int*      bfill   = (int*)(ws + carve((size_t)NB * 4));
  __half*   wt1     = (__half*)(ws + carve(16384 * 2));
  __half*   wt2     = (__half*)(ws + carve(8192 * 2));
  unsigned* slab    = (unsigned*)(ws + carve((size_t)NB * SLAB * 4));
  int*      ssrc    = (int*)(ws + carve((size_t)NB * SLAB * 4));  // fixed slabs
  __half*   h1      = (__half*)(ws + carve((size_t)N * K * 2));   // row-major
  __half*   out1    = (__half*)(ws + carve((size_t)N * K * 2));   // fp16
  if (off > ws_size) return;

  __half* h2 = h1;            // h1 dead after agg1; h2 row-major [N][64]
  float* out2 = (float*)d_out;

  k_prep<<<96, 256, 0, stream>>>(W1, W2, wt1, wt2, bfill, NB);
  const int nwg1 = (E + P1_EDGES - 1) / P1_EDGES;
  k_p1<<<nwg1, 256, 0, stream>>>(src, dst, E, NB, bfill, slab);
  k_p2<<<NB, 256, 0, stream>>>(slab, bfill, N, deg, row_ptr, dinv, ssrc);

  k_gemm<128, false><<<(N + 63) / 64, 256, 0, stream>>>(x, wt1, dinv, h1, N);
  k_agg128<<<(N + 3) / 4, 256, 0, stream>>>(h1, row_ptr, deg, ssrc, dinv, b1,
                                            out1, N);
  k_gemm<64, true><<<(N + 63) / 64, 256, 0, stream>>>(out1, wt2, dinv, h2, N);
  k_agg64<<<(N + 3) / 4, 256, 0, stream>>>(h2, row_ptr, deg, ssrc, dinv, b2,
                                           out2, N);
  (void)n_in; (void)out_size;
}